// Round 3
// baseline (136.108 us; speedup 1.0000x reference)
//
#include <hip/hip_runtime.h>
#include <math.h>

#define BB 64
#define WW 128
#define FF 64
#define HH 4
#define OW 128
#define HO 512   // H*OW

// ---------------------------------------------------------------------------
// Kernel 1: projections.  NEW layout: fs/fd are [B][HO][F] (row r = h*OW+d).
//   fs[b][r][f] = sum_k x[b][k][f] * Wsrc[r][k] + bsrc[r]
// Grid 64b x 16 rtiles (64 rows). Block 256 = 4 waves; wave owns 16 rows
// (wave-uniform via readfirstlane so W/bias reads become s_load, off the
// VMEM pipe). lane = f: x loads and stores fully coalesced dwords.
// Per 4k-chunk: 4 VMEM dword + 16 s_load_dwordx4 + 64 FMA -> VALU-bound.
// ---------------------------------------------------------------------------
__global__ __launch_bounds__(256) void gat_proj(
    const float* __restrict__ x,     // [B][W][F]
    const float* __restrict__ Wsrc,  // [512][128]
    const float* __restrict__ bsrc,
    const float* __restrict__ Wdst,
    const float* __restrict__ bdst,
    float* __restrict__ fs,          // [B][HO][F]
    float* __restrict__ fd)
{
    const int b  = blockIdx.x >> 4;
    const int rt = blockIdx.x & 15;
    const bool is_src = rt < 8;
    const int roff = (rt & 7) * 64;          // row base within this matrix's 512

    const float* Wm  = is_src ? Wsrc : Wdst;
    const float* bm  = is_src ? bsrc : bdst;
    float*       dst = is_src ? fs   : fd;

    const int lane = threadIdx.x & 63;                               // f
    const int wv   = __builtin_amdgcn_readfirstlane(threadIdx.x >> 6); // 0..3
    const int r0   = roff + wv * 16;

    const float* xb = x  + (size_t)b * WW * FF + lane;
    const float* wb = Wm + (size_t)r0 * WW;

    float acc[16] = {};
    for (int k0 = 0; k0 < WW; k0 += 4) {
        float xv[4];
        #pragma unroll
        for (int kk = 0; kk < 4; ++kk)
            xv[kk] = xb[(k0 + kk) * FF];
        #pragma unroll
        for (int rr = 0; rr < 16; ++rr) {
            float4 wr = *(const float4*)&wb[rr * WW + k0];   // uniform -> s_load
            acc[rr] = fmaf(xv[0], wr.x, acc[rr]);
            acc[rr] = fmaf(xv[1], wr.y, acc[rr]);
            acc[rr] = fmaf(xv[2], wr.z, acc[rr]);
            acc[rr] = fmaf(xv[3], wr.w, acc[rr]);
        }
    }
    #pragma unroll
    for (int rr = 0; rr < 16; ++rr)
        dst[((size_t)b * HO + r0 + rr) * FF + lane] = acc[rr] + bm[r0 + rr];
}

// ---------------------------------------------------------------------------
// Kernel 2: fused scores + edge-softmax + aggregation.
// Grid 1024 = (b, h, jblk of 16 j)  -> 4 blocks/CU, 16 waves/CU.
// Phase 1: thread = (istrip, j_l): 4 scores; fs/fd reads 1-line coalesced
//          ([d][i] layout).  lrelu(s)*a = (0.6a)*s + (0.4a)*|s|, |s| free.
// Phase 2: strip-reduced max/sum in LDS, exp in-register. No shuffles.
// Phase 3: thread = (d-group of 8, j_l), loop i; partial to ws2[b][h][d][j].
// ---------------------------------------------------------------------------
__global__ __launch_bounds__(256) void gat_attn(
    const float* __restrict__ fs,    // [B][HO][F]
    const float* __restrict__ fd,
    const float* __restrict__ attn,  // [H][OW]
    float* __restrict__ ws2)         // [B][H][OW][F]
{
    __shared__ float A6[OW], B4[OW];
    __shared__ float pL[FF][17];         // exp(score-m), padded
    __shared__ float redmax[16][16];
    __shared__ float redsum[16][16];

    const int bx = blockIdx.x;
    const int b  = bx >> 4;
    const int h  = (bx >> 2) & 3;
    const int jb = bx & 3;

    const int t      = threadIdx.x;
    const int j_l    = t & 15;
    const int istrip = t >> 4;           // 0..15
    const int i0     = istrip * 4;
    const int j      = jb * 16 + j_l;

    if (t < 32) {
        float4 av = *(const float4*)&attn[h * OW + t * 4];
        float4 a6, b4;
        a6.x = 0.6f * av.x; a6.y = 0.6f * av.y; a6.z = 0.6f * av.z; a6.w = 0.6f * av.w;
        b4.x = 0.4f * av.x; b4.y = 0.4f * av.y; b4.z = 0.4f * av.z; b4.w = 0.4f * av.w;
        *(float4*)&A6[t * 4] = a6;
        *(float4*)&B4[t * 4] = b4;
    }
    __syncthreads();

    const float* fsb = fs + ((size_t)b * HO + h * OW) * FF;
    const float* fdb = fd + ((size_t)b * HO + h * OW) * FF;

    // ---- phase 1: scores for (i0..i0+3) x j ----
    float sc[4] = {0.0f, 0.0f, 0.0f, 0.0f};
    for (int c = 0; c < 32; ++c) {
        float4 a6 = *(const float4*)&A6[c * 4];
        float4 b4 = *(const float4*)&B4[c * 4];
        #pragma unroll
        for (int dd = 0; dd < 4; ++dd) {
            const int row = c * 4 + dd;
            float4 fsv = *(const float4*)&fsb[(size_t)row * FF + i0];
            float  fdv = fdb[(size_t)row * FF + j];
            const float af = ((const float*)&a6)[dd];
            const float bf = ((const float*)&b4)[dd];
            const float* ff = (const float*)&fsv;
            #pragma unroll
            for (int m = 0; m < 4; ++m) {
                float s = ff[m] + fdv;
                sc[m] = fmaf(af, s, fmaf(bf, fabsf(s), sc[m]));
            }
        }
    }
    redmax[istrip][j_l] = fmaxf(fmaxf(sc[0], sc[1]), fmaxf(sc[2], sc[3]));
    __syncthreads();

    // ---- phase 2: softmax over i per column j ----
    float mj = -1e30f;
    #pragma unroll
    for (int s = 0; s < 16; ++s) mj = fmaxf(mj, redmax[s][j_l]);
    float ps = 0.0f;
    #pragma unroll
    for (int m = 0; m < 4; ++m) {
        float e = __expf(sc[m] - mj);
        pL[i0 + m][j_l] = e;
        ps += e;
    }
    redsum[istrip][j_l] = ps;
    __syncthreads();

    // ---- phase 3: aggregation, thread = (8 d's, j_l) ----
    const int d0 = (t >> 4) * 8;
    float ag[8] = {};
    for (int ic = 0; ic < FF; ic += 4) {
        float p[4];
        #pragma unroll
        for (int ii = 0; ii < 4; ++ii) p[ii] = pL[ic + ii][j_l];
        #pragma unroll
        for (int dd = 0; dd < 8; ++dd) {
            float4 fv = *(const float4*)&fsb[(size_t)(d0 + dd) * FF + ic];
            const float* fvf = (const float*)&fv;
            #pragma unroll
            for (int ii = 0; ii < 4; ++ii)
                ag[dd] = fmaf(p[ii], fvf[ii], ag[dd]);
        }
    }
    float ls = 0.0f;
    #pragma unroll
    for (int s = 0; s < 16; ++s) ls += redsum[s][j_l];
    const float inv = 0.25f / ls;
    #pragma unroll
    for (int dd = 0; dd < 8; ++dd)
        ws2[(((size_t)b * HH + h) * OW + d0 + dd) * FF + j] = ag[dd] * inv;
}

// ---------------------------------------------------------------------------
// Kernel 3: head-sum (0.25 folded upstream) -> out[b][d][j].
// ---------------------------------------------------------------------------
__global__ __launch_bounds__(256) void gat_reduce(
    const float* __restrict__ ws2,   // [B][H][OW][F]
    float* __restrict__ out)         // [B][OW][F]
{
    const int g = blockIdx.x * 256 + threadIdx.x;     // float4 index
    const int b   = g >> 11;                          // 2048 float4 per batch
    const int rem = (g & 2047) * 4;
    const float* base = ws2 + (size_t)b * (HH * OW * FF) + rem;
    float4 s0 = *(const float4*)(base);
    float4 s1 = *(const float4*)(base + OW * FF);
    float4 s2 = *(const float4*)(base + 2 * OW * FF);
    float4 s3 = *(const float4*)(base + 3 * OW * FF);
    float4 o;
    o.x = s0.x + s1.x + s2.x + s3.x;
    o.y = s0.y + s1.y + s2.y + s3.y;
    o.z = s0.z + s1.z + s2.z + s3.z;
    o.w = s0.w + s1.w + s2.w + s3.w;
    *(float4*)&out[(size_t)b * (OW * FF) + rem] = o;
}

// ---------------------------------------------------------------------------
extern "C" void kernel_launch(void* const* d_in, const int* in_sizes, int n_in,
                              void* d_out, int out_size, void* d_ws, size_t ws_size,
                              hipStream_t stream) {
    const float* x    = (const float*)d_in[0];
    const float* Wsrc = (const float*)d_in[1];
    const float* bsrc = (const float*)d_in[2];
    const float* Wdst = (const float*)d_in[3];
    const float* bdst = (const float*)d_in[4];
    const float* attn = (const float*)d_in[5];
    float* out = (float*)d_out;

    float* fs  = (float*)d_ws;                        // [B][HO][F] 8 MB
    float* fd  = fs  + (size_t)BB * HO * FF;          // 8 MB
    float* ws2 = fd  + (size_t)BB * HO * FF;          // 8 MB

    gat_proj  <<<BB * 16,      256, 0, stream>>>(x, Wsrc, bsrc, Wdst, bdst, fs, fd);
    gat_attn  <<<BB * HH * 4,  256, 0, stream>>>(fs, fd, attn, ws2);
    gat_reduce<<<512,          256, 0, stream>>>(ws2, out);
}